// Round 8
// baseline (206.993 us; speedup 1.0000x reference)
//
#include <hip/hip_runtime.h>
#include <math.h>

namespace {
constexpr int kB  = 2048;
constexpr int kSW = 2048;     // short width
constexpr int kLW = 8192;     // long width
constexpr int kLP = kLW / 2;  // pooled length = 4096
constexpr int kROWS = 4;      // batch rows per wave
// long:  512 row-groups x 8 position-splits (512 pooled each) = 4096 waves
// short: 512 row-groups x 4 position-splits (512 each)        = 2048 waves
constexpr int kNBLK = 6144;   // interleaved 2 long : 1 short; 24 waves/CU
}

// ------------- long branch split: conv(k=5,p=2) -> relu -> maxpool(2) -> partial dot -------------
// one 64-lane wave: 4 rows x 512 pooled positions, 2 chunks of 256 (lane*4)
__device__ __forceinline__ void long_split(
    int blk, int q, const float* __restrict__ xl, const float* __restrict__ cw,
    const float* __restrict__ cb, const float* __restrict__ lw,
    float* __restrict__ partL) {
  const int lane = threadIdx.x;
  const int b0 = blk * kROWS;

  float wgt[8][5], bias[8];   // wave-uniform -> scalar loads
#pragma unroll
  for (int c = 0; c < 8; ++c) {
#pragma unroll
    for (int k = 0; k < 5; ++k) wgt[c][k] = cw[c * 5 + k];
    bias[c] = cb[c];
  }

  float acc[kROWS][2];
#pragma unroll
  for (int r = 0; r < kROWS; ++r) { acc[r][0] = 0.f; acc[r][1] = 0.f; }

#pragma unroll
  for (int ch = 0; ch < 2; ++ch) {
    const int p0 = q * 512 + ch * 256 + lane * 4;   // pooled base (mult of 4)
    const int s  = 2 * p0;                          // conv-input base (mult of 8)

    // x windows: w[r][0..11] = x[s-2 .. s+9] (zero-padded at edges)
    float w[kROWS][12];
#pragma unroll
    for (int r = 0; r < kROWS; ++r) {
      const float* x = xl + (size_t)(b0 + r) * kLW;
      float2 hm = (p0 > 0) ? *reinterpret_cast<const float2*>(x + s - 2)
                           : make_float2(0.f, 0.f);
      float4 f0 = *reinterpret_cast<const float4*>(x + s);
      float4 f1 = *reinterpret_cast<const float4*>(x + s + 4);
      float2 f2 = (s + 8 < kLW) ? *reinterpret_cast<const float2*>(x + s + 8)
                                : make_float2(0.f, 0.f);
      w[r][0] = hm.x; w[r][1] = hm.y;
      w[r][2] = f0.x; w[r][3] = f0.y; w[r][4] = f0.z; w[r][5] = f0.w;
      w[r][6] = f1.x; w[r][7] = f1.y; w[r][8] = f1.z; w[r][9] = f1.w;
      w[r][10] = f2.x; w[r][11] = f2.y;
    }
    // linear-weight fragments
    float4 la4[8], lb4[8];
#pragma unroll
    for (int c = 0; c < 8; ++c) {
      la4[c] = *reinterpret_cast<const float4*>(lw + (size_t)c * kLP + p0);
      lb4[c] = *reinterpret_cast<const float4*>(lw + (size_t)(8 + c) * kLP + p0);
    }

#pragma unroll
    for (int c = 0; c < 8; ++c) {
      const float la[4] = {la4[c].x, la4[c].y, la4[c].z, la4[c].w};
      const float lbv[4] = {lb4[c].x, lb4[c].y, lb4[c].z, lb4[c].w};
#pragma unroll
      for (int r = 0; r < kROWS; ++r) {
#pragma unroll
        for (int u = 0; u < 4; ++u) {
          float v0 = fmaf(wgt[c][0], w[r][2 * u + 0],
                     fmaf(wgt[c][1], w[r][2 * u + 1],
                     fmaf(wgt[c][2], w[r][2 * u + 2],
                     fmaf(wgt[c][3], w[r][2 * u + 3],
                     fmaf(wgt[c][4], w[r][2 * u + 4], bias[c])))));
          float v1 = fmaf(wgt[c][0], w[r][2 * u + 1],
                     fmaf(wgt[c][1], w[r][2 * u + 2],
                     fmaf(wgt[c][2], w[r][2 * u + 3],
                     fmaf(wgt[c][3], w[r][2 * u + 4],
                     fmaf(wgt[c][4], w[r][2 * u + 5], bias[c])))));
          const float m = fmaxf(fmaxf(v0, v1), 0.f);
          acc[r][0] = fmaf(m, la[u], acc[r][0]);
          acc[r][1] = fmaf(m, lbv[u], acc[r][1]);
        }
      }
    }
  }

  // in-wave reduction, no LDS, no barrier
#pragma unroll
  for (int r = 0; r < kROWS; ++r)
#pragma unroll
    for (int o = 0; o < 2; ++o) {
#pragma unroll
      for (int off = 32; off > 0; off >>= 1)
        acc[r][o] += __shfl_down(acc[r][o], off);
    }
  if (lane == 0) {
#pragma unroll
    for (int r = 0; r < kROWS; ++r) {
      partL[(size_t)q * kB * 2 + (size_t)(b0 + r) * 2 + 0] = acc[r][0];
      partL[(size_t)q * kB * 2 + (size_t)(b0 + r) * 2 + 1] = acc[r][1];
    }
  }
}

// ------------- short branch split: conv(k=3,p=1) -> relu -> partial dot -------------
// one 64-lane wave: 4 rows x 512 positions, 2 chunks of 256 (lane*4)
__device__ __forceinline__ void short_split(
    int blk, int h, const float* __restrict__ xs, const float* __restrict__ cw,
    const float* __restrict__ cb, const float* __restrict__ lw,
    float* __restrict__ partS) {
  const int lane = threadIdx.x;
  const int b0 = blk * kROWS;

  float wgt[8][3], bias[8];
#pragma unroll
  for (int c = 0; c < 8; ++c) {
#pragma unroll
    for (int k = 0; k < 3; ++k) wgt[c][k] = cw[c * 3 + k];
    bias[c] = cb[c];
  }

  float acc[kROWS][2];
#pragma unroll
  for (int r = 0; r < kROWS; ++r) { acc[r][0] = 0.f; acc[r][1] = 0.f; }

#pragma unroll
  for (int ch = 0; ch < 2; ++ch) {
    const int p0 = h * 512 + ch * 256 + lane * 4;

    float w[kROWS][6];  // x[p0-1 .. p0+4]
#pragma unroll
    for (int r = 0; r < kROWS; ++r) {
      const float* x = xs + (size_t)(b0 + r) * kSW;
      float xm = (p0 > 0) ? x[p0 - 1] : 0.f;
      float4 f0 = *reinterpret_cast<const float4*>(x + p0);
      float xp = (p0 + 4 < kSW) ? x[p0 + 4] : 0.f;
      w[r][0] = xm;
      w[r][1] = f0.x; w[r][2] = f0.y; w[r][3] = f0.z; w[r][4] = f0.w;
      w[r][5] = xp;
    }
    float4 la4[8], lb4[8];
#pragma unroll
    for (int c = 0; c < 8; ++c) {
      la4[c] = *reinterpret_cast<const float4*>(lw + (size_t)c * kSW + p0);
      lb4[c] = *reinterpret_cast<const float4*>(lw + (size_t)(8 + c) * kSW + p0);
    }

#pragma unroll
    for (int c = 0; c < 8; ++c) {
      const float la[4] = {la4[c].x, la4[c].y, la4[c].z, la4[c].w};
      const float lbv[4] = {lb4[c].x, lb4[c].y, lb4[c].z, lb4[c].w};
#pragma unroll
      for (int r = 0; r < kROWS; ++r) {
#pragma unroll
        for (int u = 0; u < 4; ++u) {
          float v = fmaf(wgt[c][0], w[r][u],
                    fmaf(wgt[c][1], w[r][u + 1],
                    fmaf(wgt[c][2], w[r][u + 2], bias[c])));
          const float m = fmaxf(v, 0.f);
          acc[r][0] = fmaf(m, la[u], acc[r][0]);
          acc[r][1] = fmaf(m, lbv[u], acc[r][1]);
        }
      }
    }
  }

#pragma unroll
  for (int r = 0; r < kROWS; ++r)
#pragma unroll
    for (int o = 0; o < 2; ++o) {
#pragma unroll
      for (int off = 32; off > 0; off >>= 1)
        acc[r][o] += __shfl_down(acc[r][o], off);
    }
  if (lane == 0) {
#pragma unroll
    for (int r = 0; r < kROWS; ++r) {
      partS[(size_t)h * kB * 2 + (size_t)(b0 + r) * 2 + 0] = acc[r][0];
      partS[(size_t)h * kB * 2 + (size_t)(b0 + r) * 2 + 1] = acc[r][1];
    }
  }
}

// ------------- fused feature kernel: 1-wave blocks, interleaved 2 long : 1 short -------------
__global__ __launch_bounds__(64, 8) void features_kernel(
    const float* __restrict__ xs, const float* __restrict__ cs_cw,
    const float* __restrict__ cs_cb, const float* __restrict__ cs_lw,
    const float* __restrict__ xl, const float* __restrict__ cl_cw,
    const float* __restrict__ cl_cb, const float* __restrict__ cl_lw,
    float* __restrict__ partS, float* __restrict__ partL) {
  const int bid = blockIdx.x;
  const int tri = bid / 3, rem = bid % 3;
  if (rem < 2) {
    const int li = tri * 2 + rem;          // [0, 4096)
    long_split(li >> 3, li & 7, xl, cl_cw, cl_cb, cl_lw, partL);
  } else {
    const int si = tri;                    // [0, 2048)
    short_split(si >> 2, si & 3, xs, cs_cw, cs_cb, cs_lw, partS);
  }
}

// ---------------- 4-qubit statevector circuit + final linear ----------------
template <int MASK>
__device__ __forceinline__ void apply_1q(float (&ar)[16], float (&ai)[16],
                                         float u00r, float u00i, float u01r, float u01i,
                                         float u10r, float u10i, float u11r, float u11i) {
#pragma unroll
  for (int i = 0; i < 16; ++i) {
    if (!(i & MASK)) {
      const int j = i | MASK;
      const float a0r = ar[i], a0i = ai[i];
      const float a1r = ar[j], a1i = ai[j];
      ar[i] = u00r * a0r - u00i * a0i + u01r * a1r - u01i * a1i;
      ai[i] = u00r * a0i + u00i * a0r + u01r * a1i + u01i * a1r;
      ar[j] = u10r * a0r - u10i * a0i + u11r * a1r - u11i * a1i;
      ai[j] = u10r * a0i + u10i * a0r + u11r * a1i + u11i * a1r;
    }
  }
}

template <int MASK>
__device__ __forceinline__ void apply_ry(float (&ar)[16], float (&ai)[16], float half_t) {
  float s, c;
  sincosf(half_t, &s, &c);
  apply_1q<MASK>(ar, ai, c, 0.f, -s, 0.f, s, 0.f, c, 0.f);
}

// Rot(phi, theta, omega) = RZ(omega) @ RY(theta) @ RZ(phi)
template <int MASK>
__device__ __forceinline__ void apply_rot(float (&ar)[16], float (&ai)[16],
                                          float phi, float theta, float omega) {
  float st, ct; sincosf(0.5f * theta, &st, &ct);
  float sa, ca; sincosf(0.5f * (phi + omega), &sa, &ca);
  float sm, cm; sincosf(0.5f * (phi - omega), &sm, &cm);
  apply_1q<MASK>(ar, ai,
                 ct * ca, -ct * sa,
                 -st * cm, -st * sm,
                 st * cm, -st * sm,
                 ct * ca, ct * sa);
}

template <int MC, int MT>
__device__ __forceinline__ void apply_cnot(float (&ar)[16], float (&ai)[16]) {
#pragma unroll
  for (int i = 0; i < 16; ++i) {
    if ((i & MC) && !(i & MT)) {
      const int j = i | MT;
      float t;
      t = ar[i]; ar[i] = ar[j]; ar[j] = t;
      t = ai[i]; ai[i] = ai[j]; ai[j] = t;
    }
  }
}

__global__ __launch_bounds__(64) void quantum_kernel(
    const float* __restrict__ partS, const float* __restrict__ partL,
    const float* __restrict__ cs_lb, const float* __restrict__ cl_lb,
    const float* __restrict__ rw, const float* __restrict__ fcw,
    const float* __restrict__ fcb, float* __restrict__ out) {
  const int b = blockIdx.x * 64 + threadIdx.x;
  if (b >= kB) return;

  float f0 = cs_lb[0], f1 = cs_lb[1];
#pragma unroll
  for (int h = 0; h < 4; ++h) {
    f0 += partS[(size_t)h * kB * 2 + b * 2 + 0];
    f1 += partS[(size_t)h * kB * 2 + b * 2 + 1];
  }
  float f2 = cl_lb[0], f3 = cl_lb[1];
#pragma unroll
  for (int q = 0; q < 8; ++q) {
    f2 += partL[(size_t)q * kB * 2 + b * 2 + 0];
    f3 += partL[(size_t)q * kB * 2 + b * 2 + 1];
  }

  float ar[16], ai[16];
#pragma unroll
  for (int i = 0; i < 16; ++i) { ar[i] = 0.f; ai[i] = 0.f; }
  ar[0] = 1.f;

  const float kHalfPi = 1.57079632679489662f;
  apply_ry<8>(ar, ai, kHalfPi * f0);
  apply_ry<4>(ar, ai, kHalfPi * f1);
  apply_ry<2>(ar, ai, kHalfPi * f2);
  apply_ry<1>(ar, ai, kHalfPi * f3);

  // layer 0, r = 1
  apply_rot<8>(ar, ai, rw[0], rw[1], rw[2]);
  apply_rot<4>(ar, ai, rw[3], rw[4], rw[5]);
  apply_rot<2>(ar, ai, rw[6], rw[7], rw[8]);
  apply_rot<1>(ar, ai, rw[9], rw[10], rw[11]);
  apply_cnot<8, 4>(ar, ai);
  apply_cnot<4, 2>(ar, ai);
  apply_cnot<2, 1>(ar, ai);
  apply_cnot<1, 8>(ar, ai);

  // layer 1, r = 2
  apply_rot<8>(ar, ai, rw[12], rw[13], rw[14]);
  apply_rot<4>(ar, ai, rw[15], rw[16], rw[17]);
  apply_rot<2>(ar, ai, rw[18], rw[19], rw[20]);
  apply_rot<1>(ar, ai, rw[21], rw[22], rw[23]);
  apply_cnot<8, 2>(ar, ai);
  apply_cnot<4, 1>(ar, ai);
  apply_cnot<2, 8>(ar, ai);
  apply_cnot<1, 4>(ar, ai);

  // layer 2, r = 3
  apply_rot<8>(ar, ai, rw[24], rw[25], rw[26]);
  apply_rot<4>(ar, ai, rw[27], rw[28], rw[29]);
  apply_rot<2>(ar, ai, rw[30], rw[31], rw[32]);
  apply_rot<1>(ar, ai, rw[33], rw[34], rw[35]);
  apply_cnot<8, 1>(ar, ai);
  apply_cnot<4, 8>(ar, ai);
  apply_cnot<2, 4>(ar, ai);
  apply_cnot<1, 2>(ar, ai);

  float z0 = 0.f, z1 = 0.f, z2 = 0.f, z3 = 0.f;
#pragma unroll
  for (int i = 0; i < 16; ++i) {
    const float p = ar[i] * ar[i] + ai[i] * ai[i];
    z0 += (i & 8) ? -p : p;
    z1 += (i & 4) ? -p : p;
    z2 += (i & 2) ? -p : p;
    z3 += (i & 1) ? -p : p;
  }
  out[b] = fcb[0] + z0 * fcw[0] + z1 * fcw[1] + z2 * fcw[2] + z3 * fcw[3];
}

extern "C" void kernel_launch(void* const* d_in, const int* in_sizes, int n_in,
                              void* d_out, int out_size, void* d_ws, size_t ws_size,
                              hipStream_t stream) {
  const float* xs     = (const float*)d_in[0];
  const float* xl     = (const float*)d_in[1];
  const float* cs_cw  = (const float*)d_in[2];
  const float* cs_cb  = (const float*)d_in[3];
  const float* cs_lw  = (const float*)d_in[4];
  const float* cs_lb  = (const float*)d_in[5];
  const float* cl_cw  = (const float*)d_in[6];
  const float* cl_cb  = (const float*)d_in[7];
  const float* cl_lw  = (const float*)d_in[8];
  const float* cl_lb  = (const float*)d_in[9];
  const float* rw     = (const float*)d_in[10];
  const float* fcw    = (const float*)d_in[11];
  const float* fcb    = (const float*)d_in[12];
  float* out   = (float*)d_out;
  float* partS = (float*)d_ws;                  // [4][kB][2]
  float* partL = (float*)d_ws + 4 * kB * 2;     // [8][kB][2]

  hipLaunchKernelGGL(features_kernel, dim3(kNBLK), dim3(64), 0, stream,
                     xs, cs_cw, cs_cb, cs_lw,
                     xl, cl_cw, cl_cb, cl_lw, partS, partL);
  hipLaunchKernelGGL(quantum_kernel, dim3(kB / 64), dim3(64), 0, stream,
                     partS, partL, cs_lb, cl_lb, rw, fcw, fcb, out);
}

// Round 9
// 55.636 us; speedup vs baseline: 3.7205x; 3.7205x over previous
//
#include <hip/hip_runtime.h>
#include <math.h>

namespace {
constexpr int kB  = 2048;
constexpr int kSW = 2048;     // short width
constexpr int kLW = 8192;     // long width
constexpr int kLP = kLW / 2;  // pooled length = 4096
constexpr int kR  = 16;       // batch rows streamed per wave
// long:  32 position-slices (128 pooled, 2/lane) x 128 row-groups = 4096 waves
// short:  8 position-slices (256 pos, 4/lane)    x 128 row-groups = 1024 waves
constexpr int kNBLK = 5120;   // interleaved 4 long : 1 short
}

// ------------- long: conv(k=5,p=2) -> relu -> maxpool(2) -> partial dot -------------
// wave holds lw slice (8c x 2u x 2out = 32 regs), streams kR rows past it
__device__ __forceinline__ void long_slice(
    int grp, int sl, const float* __restrict__ xl, const float* __restrict__ cw,
    const float* __restrict__ cb, const float* __restrict__ lw,
    float* __restrict__ partL) {
  const int lane = threadIdx.x;
  const int b0 = grp * kR;
  const int p0 = sl * 128 + lane * 2;   // pooled base (even)
  const int s  = 2 * p0;                // conv-input base (mult of 4)

  float wgt[8][5], bias[8];
#pragma unroll
  for (int c = 0; c < 8; ++c) {
#pragma unroll
    for (int k = 0; k < 5; ++k) wgt[c][k] = cw[c * 5 + k];
    bias[c] = cb[c];
  }

  // held lw fragments: la[c][u], lb[c][u]
  float la[8][2], lb[8][2];
#pragma unroll
  for (int c = 0; c < 8; ++c) {
    float2 a2 = *reinterpret_cast<const float2*>(lw + (size_t)c * kLP + p0);
    float2 b2 = *reinterpret_cast<const float2*>(lw + (size_t)(8 + c) * kLP + p0);
    la[c][0] = a2.x; la[c][1] = a2.y;
    lb[c][0] = b2.x; lb[c][1] = b2.y;
  }

  const bool lo_ok = (p0 > 0);
  const bool hi_ok = (s + 4 < kLW);

  for (int r = 0; r < kR; ++r) {
    const float* x = xl + (size_t)(b0 + r) * kLW;
    // window W[0..7] = x[s-2 .. s+5], zero-padded at edges
    float2 hm = lo_ok ? *reinterpret_cast<const float2*>(x + s - 2)
                      : make_float2(0.f, 0.f);
    float4 f0 = *reinterpret_cast<const float4*>(x + s);
    float2 f1 = hi_ok ? *reinterpret_cast<const float2*>(x + s + 4)
                      : make_float2(0.f, 0.f);
    float W[8];
    W[0] = hm.x; W[1] = hm.y;
    W[2] = f0.x; W[3] = f0.y; W[4] = f0.z; W[5] = f0.w;
    W[6] = f1.x; W[7] = f1.y;

    float a0 = 0.f, a1 = 0.f;
#pragma unroll
    for (int c = 0; c < 8; ++c) {
#pragma unroll
      for (int u = 0; u < 2; ++u) {
        float v0 = fmaf(wgt[c][0], W[2 * u + 0],
                   fmaf(wgt[c][1], W[2 * u + 1],
                   fmaf(wgt[c][2], W[2 * u + 2],
                   fmaf(wgt[c][3], W[2 * u + 3],
                   fmaf(wgt[c][4], W[2 * u + 4], bias[c])))));
        float v1 = fmaf(wgt[c][0], W[2 * u + 1],
                   fmaf(wgt[c][1], W[2 * u + 2],
                   fmaf(wgt[c][2], W[2 * u + 3],
                   fmaf(wgt[c][3], W[2 * u + 4],
                   fmaf(wgt[c][4], W[2 * u + 5], bias[c])))));
        const float m = fmaxf(fmaxf(v0, v1), 0.f);
        a0 = fmaf(m, la[c][u], a0);
        a1 = fmaf(m, lb[c][u], a1);
      }
    }
    // in-wave reduce + write
#pragma unroll
    for (int off = 32; off > 0; off >>= 1) {
      a0 += __shfl_down(a0, off);
      a1 += __shfl_down(a1, off);
    }
    if (lane == 0)
      *reinterpret_cast<float2*>(partL + (size_t)sl * kB * 2 + (size_t)(b0 + r) * 2) =
          make_float2(a0, a1);
  }
}

// ------------- short: conv(k=3,p=1) -> relu -> partial dot -------------
// wave holds lw slice (8c x 4u x 2out = 64 regs), streams kR rows
__device__ __forceinline__ void short_slice(
    int grp, int sl, const float* __restrict__ xs, const float* __restrict__ cw,
    const float* __restrict__ cb, const float* __restrict__ lw,
    float* __restrict__ partS) {
  const int lane = threadIdx.x;
  const int b0 = grp * kR;
  const int p0 = sl * 256 + lane * 4;   // position base (mult of 4)

  float wgt[8][3], bias[8];
#pragma unroll
  for (int c = 0; c < 8; ++c) {
#pragma unroll
    for (int k = 0; k < 3; ++k) wgt[c][k] = cw[c * 3 + k];
    bias[c] = cb[c];
  }

  float la[8][4], lb[8][4];
#pragma unroll
  for (int c = 0; c < 8; ++c) {
    float4 a4 = *reinterpret_cast<const float4*>(lw + (size_t)c * kSW + p0);
    float4 b4 = *reinterpret_cast<const float4*>(lw + (size_t)(8 + c) * kSW + p0);
    la[c][0] = a4.x; la[c][1] = a4.y; la[c][2] = a4.z; la[c][3] = a4.w;
    lb[c][0] = b4.x; lb[c][1] = b4.y; lb[c][2] = b4.z; lb[c][3] = b4.w;
  }

  const bool lo_ok = (p0 > 0);
  const bool hi_ok = (p0 + 4 < kSW);

  for (int r = 0; r < kR; ++r) {
    const float* x = xs + (size_t)(b0 + r) * kSW;
    float xm = lo_ok ? x[p0 - 1] : 0.f;
    float4 f0 = *reinterpret_cast<const float4*>(x + p0);
    float xp = hi_ok ? x[p0 + 4] : 0.f;
    float W[6];
    W[0] = xm;
    W[1] = f0.x; W[2] = f0.y; W[3] = f0.z; W[4] = f0.w;
    W[5] = xp;

    float a0 = 0.f, a1 = 0.f;
#pragma unroll
    for (int c = 0; c < 8; ++c) {
#pragma unroll
      for (int u = 0; u < 4; ++u) {
        float v = fmaf(wgt[c][0], W[u],
                  fmaf(wgt[c][1], W[u + 1],
                  fmaf(wgt[c][2], W[u + 2], bias[c])));
        const float m = fmaxf(v, 0.f);
        a0 = fmaf(m, la[c][u], a0);
        a1 = fmaf(m, lb[c][u], a1);
      }
    }
#pragma unroll
    for (int off = 32; off > 0; off >>= 1) {
      a0 += __shfl_down(a0, off);
      a1 += __shfl_down(a1, off);
    }
    if (lane == 0)
      *reinterpret_cast<float2*>(partS + (size_t)sl * kB * 2 + (size_t)(b0 + r) * 2) =
          make_float2(a0, a1);
  }
}

// ------------- fused feature kernel: 1-wave blocks, interleaved 4 long : 1 short -------------
__global__ __launch_bounds__(64, 4) void features_kernel(
    const float* __restrict__ xs, const float* __restrict__ cs_cw,
    const float* __restrict__ cs_cb, const float* __restrict__ cs_lw,
    const float* __restrict__ xl, const float* __restrict__ cl_cw,
    const float* __restrict__ cl_cb, const float* __restrict__ cl_lw,
    float* __restrict__ partS, float* __restrict__ partL) {
  const int bid = blockIdx.x;
  const int grp5 = bid / 5, rem = bid % 5;
  if (rem < 4) {
    const int li = grp5 * 4 + rem;         // [0, 4096)
    long_slice(li >> 5, li & 31, xl, cl_cw, cl_cb, cl_lw, partL);
  } else {
    const int si = grp5;                   // [0, 1024)
    short_slice(si >> 3, si & 7, xs, cs_cw, cs_cb, cs_lw, partS);
  }
}

// ---------------- 4-qubit statevector circuit + final linear ----------------
template <int MASK>
__device__ __forceinline__ void apply_1q(float (&ar)[16], float (&ai)[16],
                                         float u00r, float u00i, float u01r, float u01i,
                                         float u10r, float u10i, float u11r, float u11i) {
#pragma unroll
  for (int i = 0; i < 16; ++i) {
    if (!(i & MASK)) {
      const int j = i | MASK;
      const float a0r = ar[i], a0i = ai[i];
      const float a1r = ar[j], a1i = ai[j];
      ar[i] = u00r * a0r - u00i * a0i + u01r * a1r - u01i * a1i;
      ai[i] = u00r * a0i + u00i * a0r + u01r * a1i + u01i * a1r;
      ar[j] = u10r * a0r - u10i * a0i + u11r * a1r - u11i * a1i;
      ai[j] = u10r * a0i + u10i * a0r + u11r * a1i + u11i * a1r;
    }
  }
}

template <int MASK>
__device__ __forceinline__ void apply_ry(float (&ar)[16], float (&ai)[16], float half_t) {
  float s, c;
  sincosf(half_t, &s, &c);
  apply_1q<MASK>(ar, ai, c, 0.f, -s, 0.f, s, 0.f, c, 0.f);
}

// Rot(phi, theta, omega) = RZ(omega) @ RY(theta) @ RZ(phi)
template <int MASK>
__device__ __forceinline__ void apply_rot(float (&ar)[16], float (&ai)[16],
                                          float phi, float theta, float omega) {
  float st, ct; sincosf(0.5f * theta, &st, &ct);
  float sa, ca; sincosf(0.5f * (phi + omega), &sa, &ca);
  float sm, cm; sincosf(0.5f * (phi - omega), &sm, &cm);
  apply_1q<MASK>(ar, ai,
                 ct * ca, -ct * sa,
                 -st * cm, -st * sm,
                 st * cm, -st * sm,
                 ct * ca, ct * sa);
}

template <int MC, int MT>
__device__ __forceinline__ void apply_cnot(float (&ar)[16], float (&ai)[16]) {
#pragma unroll
  for (int i = 0; i < 16; ++i) {
    if ((i & MC) && !(i & MT)) {
      const int j = i | MT;
      float t;
      t = ar[i]; ar[i] = ar[j]; ar[j] = t;
      t = ai[i]; ai[i] = ai[j]; ai[j] = t;
    }
  }
}

__global__ __launch_bounds__(64) void quantum_kernel(
    const float* __restrict__ partS, const float* __restrict__ partL,
    const float* __restrict__ cs_lb, const float* __restrict__ cl_lb,
    const float* __restrict__ rw, const float* __restrict__ fcw,
    const float* __restrict__ fcb, float* __restrict__ out) {
  const int b = blockIdx.x * 64 + threadIdx.x;
  if (b >= kB) return;

  float f0 = cs_lb[0], f1 = cs_lb[1];
#pragma unroll
  for (int sl = 0; sl < 8; ++sl) {
    float2 p = *reinterpret_cast<const float2*>(partS + (size_t)sl * kB * 2 + b * 2);
    f0 += p.x; f1 += p.y;
  }
  float f2 = cl_lb[0], f3 = cl_lb[1];
#pragma unroll
  for (int sl = 0; sl < 32; ++sl) {
    float2 p = *reinterpret_cast<const float2*>(partL + (size_t)sl * kB * 2 + b * 2);
    f2 += p.x; f3 += p.y;
  }

  float ar[16], ai[16];
#pragma unroll
  for (int i = 0; i < 16; ++i) { ar[i] = 0.f; ai[i] = 0.f; }
  ar[0] = 1.f;

  const float kHalfPi = 1.57079632679489662f;
  apply_ry<8>(ar, ai, kHalfPi * f0);
  apply_ry<4>(ar, ai, kHalfPi * f1);
  apply_ry<2>(ar, ai, kHalfPi * f2);
  apply_ry<1>(ar, ai, kHalfPi * f3);

  // layer 0, r = 1
  apply_rot<8>(ar, ai, rw[0], rw[1], rw[2]);
  apply_rot<4>(ar, ai, rw[3], rw[4], rw[5]);
  apply_rot<2>(ar, ai, rw[6], rw[7], rw[8]);
  apply_rot<1>(ar, ai, rw[9], rw[10], rw[11]);
  apply_cnot<8, 4>(ar, ai);
  apply_cnot<4, 2>(ar, ai);
  apply_cnot<2, 1>(ar, ai);
  apply_cnot<1, 8>(ar, ai);

  // layer 1, r = 2
  apply_rot<8>(ar, ai, rw[12], rw[13], rw[14]);
  apply_rot<4>(ar, ai, rw[15], rw[16], rw[17]);
  apply_rot<2>(ar, ai, rw[18], rw[19], rw[20]);
  apply_rot<1>(ar, ai, rw[21], rw[22], rw[23]);
  apply_cnot<8, 2>(ar, ai);
  apply_cnot<4, 1>(ar, ai);
  apply_cnot<2, 8>(ar, ai);
  apply_cnot<1, 4>(ar, ai);

  // layer 2, r = 3
  apply_rot<8>(ar, ai, rw[24], rw[25], rw[26]);
  apply_rot<4>(ar, ai, rw[27], rw[28], rw[29]);
  apply_rot<2>(ar, ai, rw[30], rw[31], rw[32]);
  apply_rot<1>(ar, ai, rw[33], rw[34], rw[35]);
  apply_cnot<8, 1>(ar, ai);
  apply_cnot<4, 8>(ar, ai);
  apply_cnot<2, 4>(ar, ai);
  apply_cnot<1, 2>(ar, ai);

  float z0 = 0.f, z1 = 0.f, z2 = 0.f, z3 = 0.f;
#pragma unroll
  for (int i = 0; i < 16; ++i) {
    const float p = ar[i] * ar[i] + ai[i] * ai[i];
    z0 += (i & 8) ? -p : p;
    z1 += (i & 4) ? -p : p;
    z2 += (i & 2) ? -p : p;
    z3 += (i & 1) ? -p : p;
  }
  out[b] = fcb[0] + z0 * fcw[0] + z1 * fcw[1] + z2 * fcw[2] + z3 * fcw[3];
}

extern "C" void kernel_launch(void* const* d_in, const int* in_sizes, int n_in,
                              void* d_out, int out_size, void* d_ws, size_t ws_size,
                              hipStream_t stream) {
  const float* xs     = (const float*)d_in[0];
  const float* xl     = (const float*)d_in[1];
  const float* cs_cw  = (const float*)d_in[2];
  const float* cs_cb  = (const float*)d_in[3];
  const float* cs_lw  = (const float*)d_in[4];
  const float* cs_lb  = (const float*)d_in[5];
  const float* cl_cw  = (const float*)d_in[6];
  const float* cl_cb  = (const float*)d_in[7];
  const float* cl_lw  = (const float*)d_in[8];
  const float* cl_lb  = (const float*)d_in[9];
  const float* rw     = (const float*)d_in[10];
  const float* fcw    = (const float*)d_in[11];
  const float* fcb    = (const float*)d_in[12];
  float* out   = (float*)d_out;
  float* partS = (float*)d_ws;                  // [8][kB][2]   = 128 KB
  float* partL = (float*)d_ws + 8 * kB * 2;     // [32][kB][2]  = 512 KB

  hipLaunchKernelGGL(features_kernel, dim3(kNBLK), dim3(64), 0, stream,
                     xs, cs_cw, cs_cb, cs_lw,
                     xl, cl_cw, cl_cb, cl_lw, partS, partL);
  hipLaunchKernelGGL(quantum_kernel, dim3(kB / 64), dim3(64), 0, stream,
                     partS, partL, cs_lb, cl_lb, rw, fcw, fcb, out);
}

// Round 10
// 53.381 us; speedup vs baseline: 3.8776x; 1.0422x over previous
//
#include <hip/hip_runtime.h>
#include <math.h>

namespace {
constexpr int kB  = 2048;
constexpr int kSW = 2048;      // short width
constexpr int kLW = 8192;      // long width
constexpr int kLP = kLW / 2;   // pooled length = 4096
constexpr int kLR = 16;        // batch rows per long block
constexpr int kSR = 8;         // batch rows per short block
constexpr int kLSL = 16;       // long slices (256 pooled positions each)
constexpr int kSSL = 4;        // short slices (512 positions each)
constexpr int kLBLK = kLSL * (kB / kLR);   // 16 * 128 = 2048
constexpr int kSBLK = kSSL * (kB / kSR);   // 4 * 256  = 1024
constexpr int kNBLK = kLBLK + kSBLK;       // 3072
}

// ------------- long: conv(k=5,p=2) -> relu -> maxpool(2) -> partial dot -------------
// 256 threads = 256 pooled positions; lw fragments in regs; 16 rows streamed;
// deferred reduction (one butterfly per block).
__device__ __forceinline__ void long_path(
    int sl, int rg, const float* __restrict__ xl, const float* __restrict__ cw,
    const float* __restrict__ cb, const float* __restrict__ lw,
    float* __restrict__ partL, float (*red)[32]) {
  const int t = threadIdx.x;
  const int b0 = rg * kLR;
  const int P = sl * 256 + t;          // global pooled position

  float wgt[8][5], bias[8];            // wave-uniform -> SGPRs
#pragma unroll
  for (int c = 0; c < 8; ++c) {
#pragma unroll
    for (int k = 0; k < 5; ++k) wgt[c][k] = cw[c * 5 + k];
    bias[c] = cb[c];
  }

  // lw fragments for this lane's position, held for the whole block
  float la[8], lb[8];
#pragma unroll
  for (int c = 0; c < 8; ++c) {
    la[c] = lw[(size_t)c * kLP + P];
    lb[c] = lw[(size_t)(8 + c) * kLP + P];
  }

  float acc0[kLR], acc1[kLR];
#pragma unroll
  for (int r = 0; r < kLR; ++r) { acc0[r] = 0.f; acc1[r] = 0.f; }

  const bool lo = (P > 0);
  const bool hi = (P < kLP - 1);
  const float* xb = xl + (size_t)b0 * kLW + 2 * P;

#pragma unroll
  for (int r = 0; r < kLR; ++r) {
    const float* x = xb + (size_t)r * kLW;
    // W[0..5] = x[2P-2 .. 2P+3], zero-padded at edges
    float2 A = lo ? *reinterpret_cast<const float2*>(x - 2) : make_float2(0.f, 0.f);
    float2 Bv = *reinterpret_cast<const float2*>(x);
    float2 C = hi ? *reinterpret_cast<const float2*>(x + 2) : make_float2(0.f, 0.f);
    const float W0 = A.x, W1 = A.y, W2 = Bv.x, W3 = Bv.y, W4 = C.x, W5 = C.y;
#pragma unroll
    for (int c = 0; c < 8; ++c) {
      float v0 = fmaf(wgt[c][0], W0,
                 fmaf(wgt[c][1], W1,
                 fmaf(wgt[c][2], W2,
                 fmaf(wgt[c][3], W3,
                 fmaf(wgt[c][4], W4, bias[c])))));
      float v1 = fmaf(wgt[c][0], W1,
                 fmaf(wgt[c][1], W2,
                 fmaf(wgt[c][2], W3,
                 fmaf(wgt[c][3], W4,
                 fmaf(wgt[c][4], W5, bias[c])))));
      const float m = fmaxf(fmaxf(v0, v1), 0.f);
      acc0[r] = fmaf(m, la[c], acc0[r]);
      acc1[r] = fmaf(m, lb[c], acc1[r]);
    }
  }

  // one reduction for the whole block: in-wave butterfly, then cross-wave via LDS
#pragma unroll
  for (int m = 1; m < 64; m <<= 1) {
#pragma unroll
    for (int r = 0; r < kLR; ++r) {
      acc0[r] += __shfl_xor(acc0[r], m);
      acc1[r] += __shfl_xor(acc1[r], m);
    }
  }
  const int w = t >> 6, lane = t & 63;
  if (lane == 0) {
#pragma unroll
    for (int r = 0; r < kLR; ++r) {
      red[w][r] = acc0[r];
      red[w][kLR + r] = acc1[r];
    }
  }
  __syncthreads();
  if (t < 2 * kLR) {
    const int o = t >> 4, r = t & 15;
    const float s = red[0][t] + red[1][t] + red[2][t] + red[3][t];
    partL[(size_t)sl * kB * 2 + (size_t)(b0 + r) * 2 + o] = s;
  }
}

// ------------- short: conv(k=3,p=1) -> relu -> partial dot -------------
// 256 threads x 2 positions each = 512 positions; 8 rows streamed.
__device__ __forceinline__ void short_path(
    int sl, int rg, const float* __restrict__ xs, const float* __restrict__ cw,
    const float* __restrict__ cb, const float* __restrict__ lw,
    float* __restrict__ partS, float (*red)[32]) {
  const int t = threadIdx.x;
  const int b0 = rg * kSR;
  const int q = sl * 512 + 2 * t;      // first of this lane's two positions

  float wgt[8][3], bias[8];
#pragma unroll
  for (int c = 0; c < 8; ++c) {
#pragma unroll
    for (int k = 0; k < 3; ++k) wgt[c][k] = cw[c * 3 + k];
    bias[c] = cb[c];
  }

  float la0[8], la1[8], lb0[8], lb1[8];
#pragma unroll
  for (int c = 0; c < 8; ++c) {
    float2 a = *reinterpret_cast<const float2*>(lw + (size_t)c * kSW + q);
    float2 b = *reinterpret_cast<const float2*>(lw + (size_t)(8 + c) * kSW + q);
    la0[c] = a.x; la1[c] = a.y;
    lb0[c] = b.x; lb1[c] = b.y;
  }

  float acc0[kSR], acc1[kSR];
#pragma unroll
  for (int r = 0; r < kSR; ++r) { acc0[r] = 0.f; acc1[r] = 0.f; }

  const bool lo = (q > 0);
  const bool hi = (q < kSW - 2);
  const float* xb = xs + (size_t)b0 * kSW + q;

#pragma unroll
  for (int r = 0; r < kSR; ++r) {
    const float* x = xb + (size_t)r * kSW;
    // need x[q-1 .. q+2]
    float2 A = lo ? *reinterpret_cast<const float2*>(x - 2) : make_float2(0.f, 0.f);
    float2 Bv = *reinterpret_cast<const float2*>(x);
    float2 C = hi ? *reinterpret_cast<const float2*>(x + 2) : make_float2(0.f, 0.f);
    const float W1 = A.y, W2 = Bv.x, W3 = Bv.y, W4 = C.x;
#pragma unroll
    for (int c = 0; c < 8; ++c) {
      float v0 = fmaf(wgt[c][0], W1,
                 fmaf(wgt[c][1], W2,
                 fmaf(wgt[c][2], W3, bias[c])));
      float v1 = fmaf(wgt[c][0], W2,
                 fmaf(wgt[c][1], W3,
                 fmaf(wgt[c][2], W4, bias[c])));
      const float m0 = fmaxf(v0, 0.f);
      const float m1 = fmaxf(v1, 0.f);
      acc0[r] = fmaf(m1, la1[c], fmaf(m0, la0[c], acc0[r]));
      acc1[r] = fmaf(m1, lb1[c], fmaf(m0, lb0[c], acc1[r]));
    }
  }

#pragma unroll
  for (int m = 1; m < 64; m <<= 1) {
#pragma unroll
    for (int r = 0; r < kSR; ++r) {
      acc0[r] += __shfl_xor(acc0[r], m);
      acc1[r] += __shfl_xor(acc1[r], m);
    }
  }
  const int w = t >> 6, lane = t & 63;
  if (lane == 0) {
#pragma unroll
    for (int r = 0; r < kSR; ++r) {
      red[w][r] = acc0[r];
      red[w][kSR + r] = acc1[r];
    }
  }
  __syncthreads();
  if (t < 2 * kSR) {
    const int o = t >> 3, r = t & 7;
    const float s = red[0][t] + red[1][t] + red[2][t] + red[3][t];
    partS[(size_t)sl * kB * 2 + (size_t)(b0 + r) * 2 + o] = s;
  }
}

// ------------- fused feature kernel: interleaved 2 long : 1 short -------------
__global__ __launch_bounds__(256, 4) void features_kernel(
    const float* __restrict__ xs, const float* __restrict__ cs_cw,
    const float* __restrict__ cs_cb, const float* __restrict__ cs_lw,
    const float* __restrict__ xl, const float* __restrict__ cl_cw,
    const float* __restrict__ cl_cb, const float* __restrict__ cl_lw,
    float* __restrict__ partS, float* __restrict__ partL) {
  __shared__ float red[4][32];
  const int bid = blockIdx.x;
  const int tri = bid / 3, rem = bid % 3;
  if (rem < 2) {
    const int li = tri * 2 + rem;          // [0, 2048)
    long_path(li >> 7, li & 127, xl, cl_cw, cl_cb, cl_lw, partL, red);
  } else {
    const int si = tri;                    // [0, 1024)
    short_path(si >> 8, si & 255, xs, cs_cw, cs_cb, cs_lw, partS, red);
  }
}

// ---------------- 4-qubit statevector circuit + final linear ----------------
template <int MASK>
__device__ __forceinline__ void apply_1q(float (&ar)[16], float (&ai)[16],
                                         float u00r, float u00i, float u01r, float u01i,
                                         float u10r, float u10i, float u11r, float u11i) {
#pragma unroll
  for (int i = 0; i < 16; ++i) {
    if (!(i & MASK)) {
      const int j = i | MASK;
      const float a0r = ar[i], a0i = ai[i];
      const float a1r = ar[j], a1i = ai[j];
      ar[i] = u00r * a0r - u00i * a0i + u01r * a1r - u01i * a1i;
      ai[i] = u00r * a0i + u00i * a0r + u01r * a1i + u01i * a1r;
      ar[j] = u10r * a0r - u10i * a0i + u11r * a1r - u11i * a1i;
      ai[j] = u10r * a0i + u10i * a0r + u11r * a1i + u11i * a1r;
    }
  }
}

template <int MASK>
__device__ __forceinline__ void apply_ry(float (&ar)[16], float (&ai)[16], float half_t) {
  float s, c;
  sincosf(half_t, &s, &c);
  apply_1q<MASK>(ar, ai, c, 0.f, -s, 0.f, s, 0.f, c, 0.f);
}

// Rot(phi, theta, omega) = RZ(omega) @ RY(theta) @ RZ(phi)
template <int MASK>
__device__ __forceinline__ void apply_rot(float (&ar)[16], float (&ai)[16],
                                          float phi, float theta, float omega) {
  float st, ct; sincosf(0.5f * theta, &st, &ct);
  float sa, ca; sincosf(0.5f * (phi + omega), &sa, &ca);
  float sm, cm; sincosf(0.5f * (phi - omega), &sm, &cm);
  apply_1q<MASK>(ar, ai,
                 ct * ca, -ct * sa,
                 -st * cm, -st * sm,
                 st * cm, -st * sm,
                 ct * ca, ct * sa);
}

template <int MC, int MT>
__device__ __forceinline__ void apply_cnot(float (&ar)[16], float (&ai)[16]) {
#pragma unroll
  for (int i = 0; i < 16; ++i) {
    if ((i & MC) && !(i & MT)) {
      const int j = i | MT;
      float t;
      t = ar[i]; ar[i] = ar[j]; ar[j] = t;
      t = ai[i]; ai[i] = ai[j]; ai[j] = t;
    }
  }
}

__global__ __launch_bounds__(64) void quantum_kernel(
    const float* __restrict__ partS, const float* __restrict__ partL,
    const float* __restrict__ cs_lb, const float* __restrict__ cl_lb,
    const float* __restrict__ rw, const float* __restrict__ fcw,
    const float* __restrict__ fcb, float* __restrict__ out) {
  const int b = blockIdx.x * 64 + threadIdx.x;
  if (b >= kB) return;

  float f0 = cs_lb[0], f1 = cs_lb[1];
#pragma unroll
  for (int sl = 0; sl < kSSL; ++sl) {
    float2 p = *reinterpret_cast<const float2*>(partS + (size_t)sl * kB * 2 + b * 2);
    f0 += p.x; f1 += p.y;
  }
  float f2 = cl_lb[0], f3 = cl_lb[1];
#pragma unroll
  for (int sl = 0; sl < kLSL; ++sl) {
    float2 p = *reinterpret_cast<const float2*>(partL + (size_t)sl * kB * 2 + b * 2);
    f2 += p.x; f3 += p.y;
  }

  float ar[16], ai[16];
#pragma unroll
  for (int i = 0; i < 16; ++i) { ar[i] = 0.f; ai[i] = 0.f; }
  ar[0] = 1.f;

  const float kHalfPi = 1.57079632679489662f;
  apply_ry<8>(ar, ai, kHalfPi * f0);
  apply_ry<4>(ar, ai, kHalfPi * f1);
  apply_ry<2>(ar, ai, kHalfPi * f2);
  apply_ry<1>(ar, ai, kHalfPi * f3);

  // layer 0, r = 1
  apply_rot<8>(ar, ai, rw[0], rw[1], rw[2]);
  apply_rot<4>(ar, ai, rw[3], rw[4], rw[5]);
  apply_rot<2>(ar, ai, rw[6], rw[7], rw[8]);
  apply_rot<1>(ar, ai, rw[9], rw[10], rw[11]);
  apply_cnot<8, 4>(ar, ai);
  apply_cnot<4, 2>(ar, ai);
  apply_cnot<2, 1>(ar, ai);
  apply_cnot<1, 8>(ar, ai);

  // layer 1, r = 2
  apply_rot<8>(ar, ai, rw[12], rw[13], rw[14]);
  apply_rot<4>(ar, ai, rw[15], rw[16], rw[17]);
  apply_rot<2>(ar, ai, rw[18], rw[19], rw[20]);
  apply_rot<1>(ar, ai, rw[21], rw[22], rw[23]);
  apply_cnot<8, 2>(ar, ai);
  apply_cnot<4, 1>(ar, ai);
  apply_cnot<2, 8>(ar, ai);
  apply_cnot<1, 4>(ar, ai);

  // layer 2, r = 3
  apply_rot<8>(ar, ai, rw[24], rw[25], rw[26]);
  apply_rot<4>(ar, ai, rw[27], rw[28], rw[29]);
  apply_rot<2>(ar, ai, rw[30], rw[31], rw[32]);
  apply_rot<1>(ar, ai, rw[33], rw[34], rw[35]);
  apply_cnot<8, 1>(ar, ai);
  apply_cnot<4, 8>(ar, ai);
  apply_cnot<2, 4>(ar, ai);
  apply_cnot<1, 2>(ar, ai);

  float z0 = 0.f, z1 = 0.f, z2 = 0.f, z3 = 0.f;
#pragma unroll
  for (int i = 0; i < 16; ++i) {
    const float p = ar[i] * ar[i] + ai[i] * ai[i];
    z0 += (i & 8) ? -p : p;
    z1 += (i & 4) ? -p : p;
    z2 += (i & 2) ? -p : p;
    z3 += (i & 1) ? -p : p;
  }
  out[b] = fcb[0] + z0 * fcw[0] + z1 * fcw[1] + z2 * fcw[2] + z3 * fcw[3];
}

extern "C" void kernel_launch(void* const* d_in, const int* in_sizes, int n_in,
                              void* d_out, int out_size, void* d_ws, size_t ws_size,
                              hipStream_t stream) {
  const float* xs     = (const float*)d_in[0];
  const float* xl     = (const float*)d_in[1];
  const float* cs_cw  = (const float*)d_in[2];
  const float* cs_cb  = (const float*)d_in[3];
  const float* cs_lw  = (const float*)d_in[4];
  const float* cs_lb  = (const float*)d_in[5];
  const float* cl_cw  = (const float*)d_in[6];
  const float* cl_cb  = (const float*)d_in[7];
  const float* cl_lw  = (const float*)d_in[8];
  const float* cl_lb  = (const float*)d_in[9];
  const float* rw     = (const float*)d_in[10];
  const float* fcw    = (const float*)d_in[11];
  const float* fcb    = (const float*)d_in[12];
  float* out   = (float*)d_out;
  float* partS = (float*)d_ws;                       // [4][kB][2]  = 64 KB
  float* partL = (float*)d_ws + kSSL * kB * 2;       // [16][kB][2] = 256 KB

  hipLaunchKernelGGL(features_kernel, dim3(kNBLK), dim3(256), 0, stream,
                     xs, cs_cw, cs_cb, cs_lw,
                     xl, cl_cw, cl_cb, cl_lw, partS, partL);
  hipLaunchKernelGGL(quantum_kernel, dim3(kB / 64), dim3(64), 0, stream,
                     partS, partL, cs_lb, cl_lb, rw, fcw, fcb, out);
}